// Round 1
// baseline (86.655 us; speedup 1.0000x reference)
//
#include <hip/hip_runtime.h>
#include <math.h>

// ---------------------------------------------------------------------------
// DRR forward projection (Registration): per-pixel ray march through a D^3
// volume with trilinear sampling.
//
// Decomposition:
//   setup_k (1 thread/batch): all small linear algebra (inv(rt_inv), so3_exp,
//     pivot composition, ext = rt_inv@pose, Ainv=inv(affine)) folded into
//       vox(s)  = p0 + alpha_s * (A1 @ pixh)     (A1 = Ainv3*ext3*kinv*sdd)
//       ray     =             A2 @ pixh          (A2 =       ext3*kinv*sdd)
//       seglen  = |ray| / S
//     21 floats per batch stored in d_ws.
//   drr_k: one 64-lane wave per output pixel; lanes stride over ray steps
//     (consecutive lanes = consecutive steps => small vox-z stride =>
//     coalesced gathers). Analytic slab clip against (-1, D) support box.
// ---------------------------------------------------------------------------

__device__ __forceinline__ void inv4x4(const float* m, float* inv) {
    inv[0]  =  m[5]*m[10]*m[15] - m[5]*m[11]*m[14] - m[9]*m[6]*m[15] + m[9]*m[7]*m[14] + m[13]*m[6]*m[11] - m[13]*m[7]*m[10];
    inv[4]  = -m[4]*m[10]*m[15] + m[4]*m[11]*m[14] + m[8]*m[6]*m[15] - m[8]*m[7]*m[14] - m[12]*m[6]*m[11] + m[12]*m[7]*m[10];
    inv[8]  =  m[4]*m[9]*m[15]  - m[4]*m[11]*m[13] - m[8]*m[5]*m[15] + m[8]*m[7]*m[13] + m[12]*m[5]*m[11] - m[12]*m[7]*m[9];
    inv[12] = -m[4]*m[9]*m[14]  + m[4]*m[10]*m[13] + m[8]*m[5]*m[14] - m[8]*m[6]*m[13] - m[12]*m[5]*m[10] + m[12]*m[6]*m[9];
    inv[1]  = -m[1]*m[10]*m[15] + m[1]*m[11]*m[14] + m[9]*m[2]*m[15] - m[9]*m[3]*m[14] - m[13]*m[2]*m[11] + m[13]*m[3]*m[10];
    inv[5]  =  m[0]*m[10]*m[15] - m[0]*m[11]*m[14] - m[8]*m[2]*m[15] + m[8]*m[3]*m[14] + m[12]*m[2]*m[11] - m[12]*m[3]*m[10];
    inv[9]  = -m[0]*m[9]*m[15]  + m[0]*m[11]*m[13] + m[8]*m[1]*m[15] - m[8]*m[3]*m[13] - m[12]*m[1]*m[11] + m[12]*m[3]*m[9];
    inv[13] =  m[0]*m[9]*m[14]  - m[0]*m[10]*m[13] - m[8]*m[1]*m[14] + m[8]*m[2]*m[13] + m[12]*m[1]*m[10] - m[12]*m[2]*m[9];
    inv[2]  =  m[1]*m[6]*m[15]  - m[1]*m[7]*m[14]  - m[5]*m[2]*m[15] + m[5]*m[3]*m[14] + m[13]*m[2]*m[7]  - m[13]*m[3]*m[6];
    inv[6]  = -m[0]*m[6]*m[15]  + m[0]*m[7]*m[14]  + m[4]*m[2]*m[15] - m[4]*m[3]*m[14] - m[12]*m[2]*m[7]  + m[12]*m[3]*m[6];
    inv[10] =  m[0]*m[5]*m[15]  - m[0]*m[7]*m[13]  - m[4]*m[1]*m[15] + m[4]*m[3]*m[13] + m[12]*m[1]*m[7]  - m[12]*m[3]*m[5];
    inv[14] = -m[0]*m[5]*m[14]  + m[0]*m[6]*m[13]  + m[4]*m[1]*m[14] - m[4]*m[2]*m[13] - m[12]*m[1]*m[6]  + m[12]*m[2]*m[5];
    inv[3]  = -m[1]*m[6]*m[11]  + m[1]*m[7]*m[10]  + m[5]*m[2]*m[11] - m[5]*m[3]*m[10] - m[9]*m[2]*m[7]   + m[9]*m[3]*m[6];
    inv[7]  =  m[0]*m[6]*m[11]  - m[0]*m[7]*m[10]  - m[4]*m[2]*m[11] + m[4]*m[3]*m[10] + m[8]*m[2]*m[7]   - m[8]*m[3]*m[6];
    inv[11] = -m[0]*m[5]*m[11]  + m[0]*m[7]*m[9]   + m[4]*m[1]*m[11] - m[4]*m[3]*m[9]  - m[8]*m[1]*m[7]   + m[8]*m[3]*m[5];
    inv[15] =  m[0]*m[5]*m[10]  - m[0]*m[6]*m[9]   - m[4]*m[1]*m[10] + m[4]*m[2]*m[9]  + m[8]*m[1]*m[6]   - m[8]*m[2]*m[5];
    float det = m[0]*inv[0] + m[1]*inv[4] + m[2]*inv[8] + m[3]*inv[12];
    float rd = 1.0f/det;
    for (int k = 0; k < 16; ++k) inv[k] *= rd;
}

// Per-batch params: P[b*24 + 0..8]=A1, [9..17]=A2, [18..20]=p0
__global__ void setup_k(const float* __restrict__ rt_inv, const float* __restrict__ k_inv,
                        const float* __restrict__ sdd,    const float* __restrict__ iso,
                        const float* __restrict__ affine, const float* __restrict__ rot,
                        const float* __restrict__ xyz,    float* __restrict__ P, int B)
{
    int b = blockIdx.x * blockDim.x + threadIdx.x;
    if (b >= B) return;

    const float* Mi = rt_inv + (size_t)b * 16;      // rt_inv (4x4 row-major)
    float rt[16];
    inv4x4(Mi, rt);                                  // rt = inv(rt_inv)

    float c[3];
    for (int r = 0; r < 3; ++r)
        c[r] = rt[r*4+0]*iso[0] + rt[r*4+1]*iso[1] + rt[r*4+2]*iso[2] + rt[r*4+3];

    // so3_exp(rot)
    float rx = rot[b*3+0], ry = rot[b*3+1], rz = rot[b*3+2];
    float th = sqrtf(rx*rx + ry*ry + rz*rz);
    float Rr[9];
    if (th < 1e-8f) {
        Rr[0]=1.f; Rr[1]=0.f; Rr[2]=0.f;
        Rr[3]=0.f; Rr[4]=1.f; Rr[5]=0.f;
        Rr[6]=0.f; Rr[7]=0.f; Rr[8]=1.f;
    } else {
        float kx = rx/th, ky = ry/th, kz = rz/th;
        float s = sinf(th), ct = cosf(th), v = 1.f - ct;
        Rr[0] = ct + v*kx*kx;     Rr[1] = v*kx*ky - s*kz;  Rr[2] = v*kx*kz + s*ky;
        Rr[3] = v*ky*kx + s*kz;   Rr[4] = ct + v*ky*ky;    Rr[5] = v*ky*kz - s*kx;
        Rr[6] = v*kz*kx - s*ky;   Rr[7] = v*kz*ky + s*kx;  Rr[8] = ct + v*kz*kz;
    }

    // pose = pivot(c) @ [Rr|xyz] @ pivot(-c):  rot part Rr, trans = c + xyz - Rr@c
    float tp[3];
    for (int r = 0; r < 3; ++r)
        tp[r] = c[r] + xyz[b*3+r] - (Rr[r*3+0]*c[0] + Rr[r*3+1]*c[1] + Rr[r*3+2]*c[2]);

    // ext = rt_inv @ pose  (3x3 part G, translation t)
    float G[9], t[3];
    for (int r = 0; r < 3; ++r) {
        for (int cc = 0; cc < 3; ++cc)
            G[r*3+cc] = Mi[r*4+0]*Rr[0*3+cc] + Mi[r*4+1]*Rr[1*3+cc] + Mi[r*4+2]*Rr[2*3+cc];
        t[r] = Mi[r*4+0]*tp[0] + Mi[r*4+1]*tp[1] + Mi[r*4+2]*tp[2] + Mi[r*4+3];
    }

    float Ai[16];
    inv4x4(affine, Ai);

    float p0[3];
    for (int r = 0; r < 3; ++r)
        p0[r] = Ai[r*4+0]*t[0] + Ai[r*4+1]*t[1] + Ai[r*4+2]*t[2] + Ai[r*4+3];

    float MG[9];
    for (int r = 0; r < 3; ++r)
        for (int cc = 0; cc < 3; ++cc)
            MG[r*3+cc] = Ai[r*4+0]*G[0*3+cc] + Ai[r*4+1]*G[1*3+cc] + Ai[r*4+2]*G[2*3+cc];

    const float* Ki = k_inv + (size_t)b * 9;
    float sd = sdd[b];
    float* Pb = P + (size_t)b * 24;
    for (int r = 0; r < 3; ++r)
        for (int cc = 0; cc < 3; ++cc) {
            Pb[r*3+cc]     = (MG[r*3+0]*Ki[0*3+cc] + MG[r*3+1]*Ki[1*3+cc] + MG[r*3+2]*Ki[2*3+cc]) * sd;
            Pb[9 + r*3+cc] = (G[r*3+0]*Ki[0*3+cc]  + G[r*3+1]*Ki[1*3+cc]  + G[r*3+2]*Ki[2*3+cc])  * sd;
        }
    Pb[18] = p0[0]; Pb[19] = p0[1]; Pb[20] = p0[2];
}

// One 64-lane wave per output pixel; lane l handles steps slo+l, slo+l+64, ...
__global__ void __launch_bounds__(256) drr_k(
        const float* __restrict__ vol, const float* __restrict__ P,
        float* __restrict__ out,
        const int* __restrict__ Hp, const int* __restrict__ Wp, const int* __restrict__ Sp,
        int B, int D)
{
    const int H = *Hp, W = *Wp, S = *Sp;
    const int npix = H * W;
    int gtid = blockIdx.x * blockDim.x + threadIdx.x;
    int wid  = gtid >> 6;
    int lane = gtid & 63;
    if (wid >= B * npix) return;
    int b   = wid / npix;
    int pix = wid - b * npix;
    int i   = pix / W;
    int j   = pix - i * W;

    const float* Pb = P + (size_t)b * 24;
    float px = j + 0.5f, py = i + 0.5f;
    // vox(s) = p0 + alpha*dd ; ray = (rxx,ryy,rzz)
    float ddx = fmaf(Pb[0], px, fmaf(Pb[1], py, Pb[2]));
    float ddy = fmaf(Pb[3], px, fmaf(Pb[4], py, Pb[5]));
    float ddz = fmaf(Pb[6], px, fmaf(Pb[7], py, Pb[8]));
    float rxx = fmaf(Pb[9], px, fmaf(Pb[10], py, Pb[11]));
    float ryy = fmaf(Pb[12], px, fmaf(Pb[13], py, Pb[14]));
    float rzz = fmaf(Pb[15], px, fmaf(Pb[16], py, Pb[17]));
    float p0x = Pb[18], p0y = Pb[19], p0z = Pb[20];

    float Sf = (float)S, invS = 1.0f / Sf;
    float seglen = sqrtf(rxx*rxx + ryy*ryy + rzz*rzz) * invS;

    // slab clip against nonzero-support box (-1, D) per axis (widened)
    const float lo = -1.001f, hi = (float)D + 0.001f;
    float a0 = 0.f, a1 = 1.f;
    {
        float p[3] = {p0x, p0y, p0z};
        float d[3] = {ddx, ddy, ddz};
        #pragma unroll
        for (int ax = 0; ax < 3; ++ax) {
            if (fabsf(d[ax]) > 1e-12f) {
                float r  = 1.0f / d[ax];
                float t0 = (lo - p[ax]) * r;
                float t1 = (hi - p[ax]) * r;
                float tmn = fminf(t0, t1), tmx = fmaxf(t0, t1);
                a0 = fmaxf(a0, tmn);
                a1 = fminf(a1, tmx);
            } else if (p[ax] < lo || p[ax] > hi) {
                a1 = -1.0f;  // empty
            }
        }
    }
    int slo = (int)ceilf(a0 * Sf - 0.5f) - 1;   // widen 1 step for fp safety
    int shi = (int)floorf(a1 * Sf - 0.5f) + 1;  // (extra samples compute 0)
    if (slo < 0) slo = 0;
    if (shi > S - 1) shi = S - 1;

    const int D1 = D - 1;
    float sum = 0.f;
    for (int s = slo + lane; s <= shi; s += 64) {
        float al = (s + 0.5f) * invS;
        float x = fmaf(al, ddx, p0x);
        float y = fmaf(al, ddy, p0y);
        float z = fmaf(al, ddz, p0z);
        float fx = floorf(x), fy = floorf(y), fz = floorf(z);
        int ix = (int)fx, iy = (int)fy, iz = (int)fz;
        float tx = x - fx, ty = y - fy, tz = z - fz;
        int x0 = min(max(ix, 0), D1), x1 = min(max(ix + 1, 0), D1);
        int y0 = min(max(iy, 0), D1), y1 = min(max(iy + 1, 0), D1);
        int z0 = min(max(iz, 0), D1), z1 = min(max(iz + 1, 0), D1);
        bool bx0 = (unsigned)ix       < (unsigned)D, bx1 = (unsigned)(ix + 1) < (unsigned)D;
        bool by0 = (unsigned)iy       < (unsigned)D, by1 = (unsigned)(iy + 1) < (unsigned)D;
        bool bz0 = (unsigned)iz       < (unsigned)D, bz1 = (unsigned)(iz + 1) < (unsigned)D;
        const float* p00 = vol + ((size_t)x0 * D + y0) * D;
        const float* p01 = vol + ((size_t)x0 * D + y1) * D;
        const float* p10 = vol + ((size_t)x1 * D + y0) * D;
        const float* p11 = vol + ((size_t)x1 * D + y1) * D;
        float v000 = (bx0 && by0 && bz0) ? p00[z0] : 0.f;
        float v001 = (bx0 && by0 && bz1) ? p00[z1] : 0.f;
        float v010 = (bx0 && by1 && bz0) ? p01[z0] : 0.f;
        float v011 = (bx0 && by1 && bz1) ? p01[z1] : 0.f;
        float v100 = (bx1 && by0 && bz0) ? p10[z0] : 0.f;
        float v101 = (bx1 && by0 && bz1) ? p10[z1] : 0.f;
        float v110 = (bx1 && by1 && bz0) ? p11[z0] : 0.f;
        float v111 = (bx1 && by1 && bz1) ? p11[z1] : 0.f;
        float c00 = fmaf(tz, v001 - v000, v000);
        float c01 = fmaf(tz, v011 - v010, v010);
        float c10 = fmaf(tz, v101 - v100, v100);
        float c11 = fmaf(tz, v111 - v110, v110);
        float c0  = fmaf(ty, c01 - c00, c00);
        float c1  = fmaf(ty, c11 - c10, c10);
        sum += fmaf(tx, c1 - c0, c0);
    }

    // deterministic wave-wide butterfly reduction
    #pragma unroll
    for (int off = 32; off > 0; off >>= 1)
        sum += __shfl_xor(sum, off, 64);

    if (lane == 0) out[(size_t)b * npix + pix] = sum * seglen;
}

extern "C" void kernel_launch(void* const* d_in, const int* in_sizes, int n_in,
                              void* d_out, int out_size, void* d_ws, size_t ws_size,
                              hipStream_t stream)
{
    const float* volume = (const float*)d_in[0];
    const float* rt_inv = (const float*)d_in[1];
    const float* k_inv  = (const float*)d_in[2];
    const float* sdd    = (const float*)d_in[3];
    const float* iso    = (const float*)d_in[4];
    const float* affine = (const float*)d_in[5];
    const float* rot    = (const float*)d_in[6];
    const float* xyz    = (const float*)d_in[7];
    const int*   Hp     = (const int*)d_in[8];
    const int*   Wp     = (const int*)d_in[9];
    const int*   Sp     = (const int*)d_in[10];

    int B = in_sizes[1] / 16;                         // rt_inv is (B,4,4)
    int D = (int)lroundf(cbrtf((float)in_sizes[0]));  // volume is (D,D,D)

    float* P = (float*)d_ws;                          // 24 floats per batch
    setup_k<<<(B + 63) / 64, 64, 0, stream>>>(rt_inv, k_inv, sdd, iso, affine, rot, xyz, P, B);

    // one wave (64 lanes) per output pixel; out_size == B*H*W
    long long threads = (long long)out_size * 64;
    int block = 256;
    long long grid = (threads + block - 1) / block;
    drr_k<<<(int)grid, block, 0, stream>>>(volume, P, (float*)d_out, Hp, Wp, Sp, B, D);
}

// Round 3
// 40.508 us; speedup vs baseline: 2.1392x; 2.1392x over previous
//
#include <hip/hip_runtime.h>
#include <math.h>

// ---------------------------------------------------------------------------
// DRR forward projection: per-pixel ray march through D^3 volume, trilinear.
//
// setup_k: folds all small linear algebra into 21 per-batch floats:
//   vox(s) = p0 + alpha_s*(A1@pixh), ray = A2@pixh, seglen = |ray|/S.
//
// drr2: 1 wave = 4 pixels (1x4 strip), 16 lanes/pixel striding over steps.
//   - analytic slab clip to the (-1,D) support box (outside = exact 0)
//   - fixed 6-iteration unrolled gather loop (96 step slots) -> all 24
//     pair-gathers in flight before first consume (latency hiding)
//   - z-corner pair loaded as one 8B load (clamped base + branchless select)
//   - x/y out-of-bounds folded into lerp weights (matches reference inb)
//   - XCD-aware 64x64-pixel supertile swizzle: blocks of one supertile land
//     on one XCD -> ray-cone working set (<1MB) fits 4MiB per-XCD L2
// ---------------------------------------------------------------------------

typedef float f2 __attribute__((ext_vector_type(2), aligned(4)));

__device__ __forceinline__ void inv4x4(const float* m, float* inv) {
    inv[0]  =  m[5]*m[10]*m[15] - m[5]*m[11]*m[14] - m[9]*m[6]*m[15] + m[9]*m[7]*m[14] + m[13]*m[6]*m[11] - m[13]*m[7]*m[10];
    inv[4]  = -m[4]*m[10]*m[15] + m[4]*m[11]*m[14] + m[8]*m[6]*m[15] - m[8]*m[7]*m[14] - m[12]*m[6]*m[11] + m[12]*m[7]*m[10];
    inv[8]  =  m[4]*m[9]*m[15]  - m[4]*m[11]*m[13] - m[8]*m[5]*m[15] + m[8]*m[7]*m[13] + m[12]*m[5]*m[11] - m[12]*m[7]*m[9];
    inv[12] = -m[4]*m[9]*m[14]  + m[4]*m[10]*m[13] + m[8]*m[5]*m[14] - m[8]*m[6]*m[13] - m[12]*m[5]*m[10] + m[12]*m[6]*m[9];
    inv[1]  = -m[1]*m[10]*m[15] + m[1]*m[11]*m[14] + m[9]*m[2]*m[15] - m[9]*m[3]*m[14] - m[13]*m[2]*m[11] + m[13]*m[3]*m[10];
    inv[5]  =  m[0]*m[10]*m[15] - m[0]*m[11]*m[14] - m[8]*m[2]*m[15] + m[8]*m[3]*m[14] + m[12]*m[2]*m[11] - m[12]*m[3]*m[10];
    inv[9]  = -m[0]*m[9]*m[15]  + m[0]*m[11]*m[13] + m[8]*m[1]*m[15] - m[8]*m[3]*m[13] - m[12]*m[1]*m[11] + m[12]*m[3]*m[9];
    inv[13] =  m[0]*m[9]*m[14]  - m[0]*m[10]*m[13] - m[8]*m[1]*m[14] + m[8]*m[2]*m[13] + m[12]*m[1]*m[10] - m[12]*m[2]*m[9];
    inv[2]  =  m[1]*m[6]*m[15]  - m[1]*m[7]*m[14]  - m[5]*m[2]*m[15] + m[5]*m[3]*m[14] + m[13]*m[2]*m[7]  - m[13]*m[3]*m[6];
    inv[6]  = -m[0]*m[6]*m[15]  + m[0]*m[7]*m[14]  + m[4]*m[2]*m[15] - m[4]*m[3]*m[14] - m[12]*m[2]*m[7]  + m[12]*m[3]*m[6];
    inv[10] =  m[0]*m[5]*m[15]  - m[0]*m[7]*m[13]  - m[4]*m[1]*m[15] + m[4]*m[3]*m[13] + m[12]*m[1]*m[7]  - m[12]*m[3]*m[5];
    inv[14] = -m[0]*m[5]*m[14]  + m[0]*m[6]*m[13]  + m[4]*m[1]*m[14] - m[4]*m[2]*m[13] - m[12]*m[1]*m[6]  + m[12]*m[2]*m[5];
    inv[3]  = -m[1]*m[6]*m[11]  + m[1]*m[7]*m[10]  + m[5]*m[2]*m[11] - m[5]*m[3]*m[10] - m[9]*m[2]*m[7]   + m[9]*m[3]*m[6];
    inv[7]  =  m[0]*m[6]*m[11]  - m[0]*m[7]*m[10]  - m[4]*m[2]*m[11] + m[4]*m[3]*m[10] + m[8]*m[2]*m[7]   - m[8]*m[3]*m[6];
    inv[11] = -m[0]*m[5]*m[11]  + m[0]*m[7]*m[9]   + m[4]*m[1]*m[11] - m[4]*m[3]*m[9]  - m[8]*m[1]*m[7]   + m[8]*m[3]*m[5];
    inv[15] =  m[0]*m[5]*m[10]  - m[0]*m[6]*m[9]   - m[4]*m[1]*m[10] + m[4]*m[2]*m[9]  + m[8]*m[1]*m[6]   - m[8]*m[2]*m[5];
    float det = m[0]*inv[0] + m[1]*inv[4] + m[2]*inv[8] + m[3]*inv[12];
    float rd = 1.0f/det;
    for (int k = 0; k < 16; ++k) inv[k] *= rd;
}

// Per-batch params: P[b*24 + 0..8]=A1, [9..17]=A2, [18..20]=p0
__global__ void setup_k(const float* __restrict__ rt_inv, const float* __restrict__ k_inv,
                        const float* __restrict__ sdd,    const float* __restrict__ iso,
                        const float* __restrict__ affine, const float* __restrict__ rot,
                        const float* __restrict__ xyz,    float* __restrict__ P, int B)
{
    int b = blockIdx.x * blockDim.x + threadIdx.x;
    if (b >= B) return;

    const float* Mi = rt_inv + (size_t)b * 16;
    float rt[16];
    inv4x4(Mi, rt);

    float c[3];
    for (int r = 0; r < 3; ++r)
        c[r] = rt[r*4+0]*iso[0] + rt[r*4+1]*iso[1] + rt[r*4+2]*iso[2] + rt[r*4+3];

    float rx = rot[b*3+0], ry = rot[b*3+1], rz = rot[b*3+2];
    float th = sqrtf(rx*rx + ry*ry + rz*rz);
    float Rr[9];
    if (th < 1e-8f) {
        Rr[0]=1.f; Rr[1]=0.f; Rr[2]=0.f;
        Rr[3]=0.f; Rr[4]=1.f; Rr[5]=0.f;
        Rr[6]=0.f; Rr[7]=0.f; Rr[8]=1.f;
    } else {
        float kx = rx/th, ky = ry/th, kz = rz/th;
        float s = sinf(th), ct = cosf(th), v = 1.f - ct;
        Rr[0] = ct + v*kx*kx;     Rr[1] = v*kx*ky - s*kz;  Rr[2] = v*kx*kz + s*ky;
        Rr[3] = v*ky*kx + s*kz;   Rr[4] = ct + v*ky*ky;    Rr[5] = v*ky*kz - s*kx;
        Rr[6] = v*kz*kx - s*ky;   Rr[7] = v*kz*ky + s*kx;  Rr[8] = ct + v*kz*kz;
    }

    float tp[3];
    for (int r = 0; r < 3; ++r)
        tp[r] = c[r] + xyz[b*3+r] - (Rr[r*3+0]*c[0] + Rr[r*3+1]*c[1] + Rr[r*3+2]*c[2]);

    float G[9], t[3];
    for (int r = 0; r < 3; ++r) {
        for (int cc = 0; cc < 3; ++cc)
            G[r*3+cc] = Mi[r*4+0]*Rr[0*3+cc] + Mi[r*4+1]*Rr[1*3+cc] + Mi[r*4+2]*Rr[2*3+cc];
        t[r] = Mi[r*4+0]*tp[0] + Mi[r*4+1]*tp[1] + Mi[r*4+2]*tp[2] + Mi[r*4+3];
    }

    float Ai[16];
    inv4x4(affine, Ai);

    float p0[3];
    for (int r = 0; r < 3; ++r)
        p0[r] = Ai[r*4+0]*t[0] + Ai[r*4+1]*t[1] + Ai[r*4+2]*t[2] + Ai[r*4+3];

    float MG[9];
    for (int r = 0; r < 3; ++r)
        for (int cc = 0; cc < 3; ++cc)
            MG[r*3+cc] = Ai[r*4+0]*G[0*3+cc] + Ai[r*4+1]*G[1*3+cc] + Ai[r*4+2]*G[2*3+cc];

    const float* Ki = k_inv + (size_t)b * 9;
    float sd = sdd[b];
    float* Pb = P + (size_t)b * 24;
    for (int r = 0; r < 3; ++r)
        for (int cc = 0; cc < 3; ++cc) {
            Pb[r*3+cc]     = (MG[r*3+0]*Ki[0*3+cc] + MG[r*3+1]*Ki[1*3+cc] + MG[r*3+2]*Ki[2*3+cc]) * sd;
            Pb[9 + r*3+cc] = (G[r*3+0]*Ki[0*3+cc]  + G[r*3+1]*Ki[1*3+cc]  + G[r*3+2]*Ki[2*3+cc])  * sd;
        }
    Pb[18] = p0[0]; Pb[19] = p0[1]; Pb[20] = p0[2];
}

// 1 wave = 4 pixels (1x4 strip); lane = 16*p + t; lane t strides steps.
// Block (256 thr, 4 waves) owns a 4x4 pixel patch; 256 blocks = one 64x64
// supertile; supertiles chunked per XCD via bid&7.
__global__ void __launch_bounds__(256, 3) drr2(
        const float* __restrict__ vol, const float* __restrict__ P,
        float* __restrict__ out,
        const int* __restrict__ Hp, const int* __restrict__ Wp, const int* __restrict__ Sp,
        int B, int D)
{
    const int H = *Hp, W = *Wp, S = *Sp;
    const int npix = H * W;
    const int nSj = (W + 63) >> 6, nSi = (H + 63) >> 6;
    const int nS = nSi * nSj;
    const int nStot = B * nS;
    const long long nVB = (long long)nStot << 8;   // 256 blocks per supertile

    const int tid  = threadIdx.x;
    const int wave = tid >> 6, lane = tid & 63;
    const int p    = lane >> 4, t = lane & 15;
    const int D1   = D - 1;
    const float Sf = (float)S, invS = 1.0f / Sf;

    for (long long vb = blockIdx.x; vb < nVB; vb += gridDim.x) {
        int st, within;
        if ((nStot & 7) == 0) {
            int xcd = (int)(vb & 7);
            long long slot = vb >> 3;
            st = xcd * (nStot >> 3) + (int)(slot >> 8);
            within = (int)(slot & 255);
        } else {
            st = (int)(vb >> 8);
            within = (int)(vb & 255);
        }
        int b = 0, stl = st;
        if (B > 1) { b = st / nS; stl = st - b * nS; }
        int si = stl / nSj, sj = stl - si * nSj;

        int r0 = (si << 6) + ((within >> 4) << 2) + wave;   // row
        int c0 = (sj << 6) + ((within & 15) << 2) + p;      // col
        bool valid = (r0 < H) && (c0 < W);
        int rr = min(r0, H - 1), cc = min(c0, W - 1);

        const float* Pb = P + 24 * __builtin_amdgcn_readfirstlane(b);
        float px = cc + 0.5f, py = rr + 0.5f;
        float ddx = fmaf(Pb[0], px, fmaf(Pb[1], py, Pb[2]));
        float ddy = fmaf(Pb[3], px, fmaf(Pb[4], py, Pb[5]));
        float ddz = fmaf(Pb[6], px, fmaf(Pb[7], py, Pb[8]));
        float rxx = fmaf(Pb[9], px, fmaf(Pb[10], py, Pb[11]));
        float ryy = fmaf(Pb[12], px, fmaf(Pb[13], py, Pb[14]));
        float rzz = fmaf(Pb[15], px, fmaf(Pb[16], py, Pb[17]));
        float p0x = Pb[18], p0y = Pb[19], p0z = Pb[20];

        float seglen = sqrtf(rxx*rxx + ryy*ryy + rzz*rzz) * invS;

        // slab clip to support box (-1, D), widened
        const float lo = -1.001f, hi = (float)D + 0.001f;
        float a0 = 0.f, a1 = 1.f;
        {
            float pp[3] = {p0x, p0y, p0z};
            float dd[3] = {ddx, ddy, ddz};
            #pragma unroll
            for (int ax = 0; ax < 3; ++ax) {
                if (fabsf(dd[ax]) > 1e-12f) {
                    float r  = 1.0f / dd[ax];
                    float t0 = (lo - pp[ax]) * r;
                    float t1 = (hi - pp[ax]) * r;
                    a0 = fmaxf(a0, fminf(t0, t1));
                    a1 = fminf(a1, fmaxf(t0, t1));
                } else if (pp[ax] < lo || pp[ax] > hi) {
                    a1 = -1.0f;
                }
            }
        }
        int slo = (int)ceilf(a0 * Sf - 0.5f) - 1;
        int shi = (int)floorf(a1 * Sf - 0.5f) + 1;
        if (slo < 0) slo = 0;
        if (shi > S - 1) shi = S - 1;

        float sum = 0.f;

        auto SAMPLE = [&](int s) {
            float act = (s <= shi) ? 1.0f : 0.0f;
            float al = (s + 0.5f) * invS;
            float x = fmaf(al, ddx, p0x);
            float y = fmaf(al, ddy, p0y);
            float z = fmaf(al, ddz, p0z);
            float fx = floorf(x), fy = floorf(y), fz = floorf(z);
            int ix = (int)fx, iy = (int)fy, iz = (int)fz;
            float tx = x - fx, ty = y - fy, tz = z - fz;
            int x0c = min(max(ix, 0), D1),     x1c = min(max(ix + 1, 0), D1);
            int y0c = min(max(iy, 0), D1),     y1c = min(max(iy + 1, 0), D1);
            int z0c = min(max(iz, 0), D - 2);
            int a0r = x0c * D, a1r = x1c * D;
            const float* b00 = vol + (size_t)((a0r + y0c) * D + z0c);
            const float* b01 = vol + (size_t)((a0r + y1c) * D + z0c);
            const float* b10 = vol + (size_t)((a1r + y0c) * D + z0c);
            const float* b11 = vol + (size_t)((a1r + y1c) * D + z0c);
            f2 q00 = *(const f2*)b00;
            f2 q01 = *(const f2*)b01;
            f2 q10 = *(const f2*)b10;
            f2 q11 = *(const f2*)b11;
            bool e0 = (iz == z0c), em = (iz == z0c - 1), ep = (iz == z0c + 1);
            // value at iz: e0 -> q.x ; iz==z0c+1 (only when iz==D-1) -> q.y ; else 0
            // value at iz+1: e0 -> q.y ; iz==z0c-1 (only when iz==-1) -> q.x ; else 0
            float v0, v1, c00, c01, c10, c11;
            v0 = e0 ? q00.x : (ep ? q00.y : 0.f);
            v1 = e0 ? q00.y : (em ? q00.x : 0.f);
            c00 = fmaf(tz, v1 - v0, v0);
            v0 = e0 ? q01.x : (ep ? q01.y : 0.f);
            v1 = e0 ? q01.y : (em ? q01.x : 0.f);
            c01 = fmaf(tz, v1 - v0, v0);
            v0 = e0 ? q10.x : (ep ? q10.y : 0.f);
            v1 = e0 ? q10.y : (em ? q10.x : 0.f);
            c10 = fmaf(tz, v1 - v0, v0);
            v0 = e0 ? q11.x : (ep ? q11.y : 0.f);
            v1 = e0 ? q11.y : (em ? q11.x : 0.f);
            c11 = fmaf(tz, v1 - v0, v0);
            float wy0 = ((unsigned)iy       < (unsigned)D) ? 1.f - ty : 0.f;
            float wy1 = ((unsigned)(iy + 1) < (unsigned)D) ? ty       : 0.f;
            float wx0 = ((unsigned)ix       < (unsigned)D) ? 1.f - tx : 0.f;
            float wx1 = ((unsigned)(ix + 1) < (unsigned)D) ? tx       : 0.f;
            float s0 = fmaf(wy0, c00, wy1 * c01);
            float s1 = fmaf(wy0, c10, wy1 * c11);
            sum = fmaf(act * wx0, s0, sum);
            sum = fmaf(act * wx1, s1, sum);
        };

        #pragma unroll
        for (int it = 0; it < 6; ++it)
            SAMPLE(slo + t + (it << 4));
        // generic tail (never taken for paths <= 96 steps)
        for (int s = slo + 96 + t; s <= shi; s += 16)
            SAMPLE(s);

        sum += __shfl_xor(sum, 8, 16);
        sum += __shfl_xor(sum, 4, 16);
        sum += __shfl_xor(sum, 2, 16);
        sum += __shfl_xor(sum, 1, 16);

        if (t == 0 && valid)
            out[(size_t)b * npix + (size_t)rr * W + cc] = sum * seglen;
    }
}

extern "C" void kernel_launch(void* const* d_in, const int* in_sizes, int n_in,
                              void* d_out, int out_size, void* d_ws, size_t ws_size,
                              hipStream_t stream)
{
    const float* volume = (const float*)d_in[0];
    const float* rt_inv = (const float*)d_in[1];
    const float* k_inv  = (const float*)d_in[2];
    const float* sdd    = (const float*)d_in[3];
    const float* iso    = (const float*)d_in[4];
    const float* affine = (const float*)d_in[5];
    const float* rot    = (const float*)d_in[6];
    const float* xyz    = (const float*)d_in[7];
    const int*   Hp     = (const int*)d_in[8];
    const int*   Wp     = (const int*)d_in[9];
    const int*   Sp     = (const int*)d_in[10];

    int B = in_sizes[1] / 16;                         // rt_inv is (B,4,4)
    int D = (int)lroundf(cbrtf((float)in_sizes[0]));  // volume is (D,D,D)

    float* P = (float*)d_ws;
    setup_k<<<(B + 63) / 64, 64, 0, stream>>>(rt_inv, k_inv, sdd, iso, affine, rot, xyz, P, B);

    // grid: one block per 4x4-pixel patch (assumes H,W multiples handled by
    // device-side grid-stride; exact when 64 | H,W)
    long long hw = (long long)out_size / B;
    long long vbl = (long long)B * ((hw + 4095) >> 12) * 256;
    if (vbl > (1 << 22)) vbl = (1 << 22);
    drr2<<<(int)vbl, 256, 0, stream>>>(volume, P, (float*)d_out, Hp, Wp, Sp, B, D);
}